// Round 9
// baseline (878.841 us; speedup 1.0000x reference)
//
#include <hip/hip_runtime.h>
#include <hip/hip_bf16.h>
#include <stdint.h>

// Problem dims
#define Bn 16384
#define Cn 512
#define Dn 512
#define Hn 1024

// a = 1 - 0.95^32 (closed-form Langevin: u32 = -a*e + Z)
#define A32 0.80628851f

typedef __attribute__((ext_vector_type(8))) short bf16x8;   // 8 bf16 (4 VGPRs)
typedef __attribute__((ext_vector_type(4))) float f32x4;    // MFMA accum
typedef __attribute__((ext_vector_type(2))) float f32x2;    // packed fp32 pair

// f32 -> bf16 RTNE (manual; inputs are finite)
__device__ __forceinline__ ushort f2bf(float f) {
  uint32_t u = __float_as_uint(f);
  return (ushort)((u + 0x7fffu + ((u >> 16) & 1u)) >> 16);
}
__device__ __forceinline__ float b2f(ushort u) {
  return __uint_as_float((uint32_t)u << 16);
}

// ---------------------------------------------------------------------------
// COMPILE-TIME threefry2x32 key schedule (partitionable JAX, verified round 4).
// All 128 key words become instruction-stream literals — no loads in hot loops.
// ---------------------------------------------------------------------------
constexpr uint32_t crotl(uint32_t v, int s) {
  return (v << s) | (v >> (32 - s));
}
struct TFOut { uint32_t w0, w1; };
constexpr TFOut ctf(uint32_t k0, uint32_t k1, uint32_t x0, uint32_t x1) {
  const uint32_t ks[3] = {k0, k1, k0 ^ k1 ^ 0x1BD11BDAu};
  const int rot[8] = {13, 15, 26, 6, 17, 29, 16, 24};
  uint32_t a = x0 + k0, b = x1 + k1;
  for (int g = 0; g < 5; ++g) {
    for (int i = 0; i < 4; ++i) {
      int r = rot[(g & 1) * 4 + i];
      a += b; b = crotl(b, r); b ^= a;
    }
    a += ks[(g + 1) % 3];
    b += ks[(g + 2) % 3] + (uint32_t)(g + 1);
  }
  return {a, b};
}
struct KeySched { uint32_t s[64]; uint32_t d[64]; };
constexpr KeySched make_keys() {
  KeySched K{};
  TFOut k1 = ctf(0u, 42u, 0u, 0u);  // split(key(42))[0]
  TFOut k2 = ctf(0u, 42u, 0u, 1u);  // split(key(42))[1]
  for (uint32_t t = 0; t < 32; ++t) {
    TFOut ws = ctf(k1.w0, k1.w1, 0u, t);
    K.s[2 * t] = ws.w0; K.s[2 * t + 1] = ws.w1;
    TFOut wd = ctf(k2.w0, k2.w1, 0u, t);
    K.d[2 * t] = wd.w0; K.d[2 * t + 1] = wd.w1;
  }
  return K;
}
constexpr KeySched KS = make_keys();

// ---------------------------------------------------------------------------
// Device threefry with literal keys: x0 = 0, x1 = j; returns w0 ^ w1.
// ---------------------------------------------------------------------------
__device__ __forceinline__ uint32_t rotl32(uint32_t v, int s) {
  return __builtin_rotateleft32(v, (uint32_t)s);
}
__device__ __forceinline__ uint32_t tf_xor(uint32_t K0, uint32_t K1,
                                           uint32_t KX, uint32_t j) {
  uint32_t a = K0, b = K1 + j;
#define TR(r) { a += b; b = rotl32(b, (r)); b ^= a; }
  TR(13) TR(15) TR(26) TR(6)   a += K1; b += KX + 1u;
  TR(17) TR(29) TR(16) TR(24)  a += KX; b += K0 + 2u;
  TR(13) TR(15) TR(26) TR(6)   a += K0; b += K1 + 3u;
  TR(17) TR(29) TR(16) TR(24)  a += K1; b += KX + 4u;
  TR(13) TR(15) TR(26) TR(6)   a += KX; b += K0 + 5u;
#undef TR
  return a ^ b;
}

// Exact (branchy) bits->normal — static-mask path (verified).
__device__ __forceinline__ float bits_to_normal(uint32_t bits) {
  float f = __uint_as_float((bits >> 9) | 0x3f800000u) - 1.0f;
  float x = f * 2.0f - 0x1.fffffep-1f;
  float w = -__logf(1.0f - x * x);
  float p;
  if (w < 5.0f) {
    w -= 2.5f;
    p =            2.81022636e-08f;
    p = fmaf(p, w, 3.43273939e-07f);
    p = fmaf(p, w, -3.5233877e-06f);
    p = fmaf(p, w, -4.39150654e-06f);
    p = fmaf(p, w, 0.00021858087f);
    p = fmaf(p, w, -0.00125372503f);
    p = fmaf(p, w, -0.00417768164f);
    p = fmaf(p, w, 0.246640727f);
    p = fmaf(p, w, 1.50140941f);
  } else {
    w = sqrtf(w) - 3.0f;
    p =            -0.000200214257f;
    p = fmaf(p, w, 0.000100950558f);
    p = fmaf(p, w, 0.00134934322f);
    p = fmaf(p, w, -0.00367342844f);
    p = fmaf(p, w, 0.00573950773f);
    p = fmaf(p, w, -0.0076224613f);
    p = fmaf(p, w, 0.00943887047f);
    p = fmaf(p, w, 1.00167406f);
    p = fmaf(p, w, 2.83297682f);
  }
  return 0x1.6a09e6p+0f * (p * x);
}

// ---------------------------------------------------------------------------
// Static mask: compsT[j] = bf16(|vc| * sigmoid(-u(e_sp))) — full unroll,
// literal keys, exact normal.
// ---------------------------------------------------------------------------
__global__ __launch_bounds__(256) void k_smask(
    const float* __restrict__ vc, const float* __restrict__ e_sp,
    ushort* __restrict__ compsT) {
  uint32_t jj = blockIdx.x * 256 + threadIdx.x;  // j = d*C + c
  uint32_t c = jj & (Cn - 1), d = jj >> 9;
  uint32_t ridx = c * Dn + d;
  float e = e_sp[ridx];
  float u = 0.0f;
#pragma unroll
  for (int t = 0; t < 32; ++t) {
    const uint32_t K0 = KS.s[2 * t], K1 = KS.s[2 * t + 1];
    uint32_t s = tf_xor(K0, K1, K0 ^ K1 ^ 0x1BD11BDAu, ridx);
    float n = bits_to_normal(s);
    u = (u - 0.05f * (u + e)) + 0.1f * n;
  }
  float gt = 1.0f / (1.0f + __expf(u));
  compsT[jj] = f2bf(fabsf(vc[ridx]) * gt);
}

// ---------------------------------------------------------------------------
// Z path: 1 elem/thread, fully unrolled 16 double-steps. Two independent
// threefry chains per iteration (int ILP), f32x2-packed erfinv tails
// (v_pk_fma_f32). Bitwise-identical per-element math to round 8 (validated).
// ---------------------------------------------------------------------------
__device__ __forceinline__ void zdyn_block(ushort* __restrict__ Z, uint32_t rb) {
  const uint32_t j = rb * 256u + threadIdx.x;
  float z = 0.0f;
#pragma unroll
  for (int t = 0; t < 32; t += 2) {
    const uint32_t Ka0 = KS.d[2 * t],     Ka1 = KS.d[2 * t + 1];
    const uint32_t Kb0 = KS.d[2 * t + 2], Kb1 = KS.d[2 * t + 3];
    uint32_t s0 = tf_xor(Ka0, Ka1, Ka0 ^ Ka1 ^ 0x1BD11BDAu, j);
    uint32_t s1 = tf_xor(Kb0, Kb1, Kb0 ^ Kb1 ^ 0x1BD11BDAu, j);
    float f0 = __uint_as_float((s0 >> 9) | 0x3f800000u) - 1.0f;
    float f1 = __uint_as_float((s1 >> 9) | 0x3f800000u) - 1.0f;
    float x0 = f0 * 2.0f - 0x1.fffffep-1f;
    float x1 = f1 * 2.0f - 0x1.fffffep-1f;
    float w0 = fminf(-__logf(fmaf(-x0, x0, 1.0f)), 5.0f) - 2.5f;
    float w1 = fminf(-__logf(fmaf(-x1, x1, 1.0f)), 5.0f) - 2.5f;
    f32x2 X = {x0, x1}, W = {w0, w1};
    f32x2 P = {2.81022636e-08f, 2.81022636e-08f};
    P = __builtin_elementwise_fma(P, W, (f32x2){3.43273939e-07f, 3.43273939e-07f});
    P = __builtin_elementwise_fma(P, W, (f32x2){-3.5233877e-06f, -3.5233877e-06f});
    P = __builtin_elementwise_fma(P, W, (f32x2){-4.39150654e-06f, -4.39150654e-06f});
    P = __builtin_elementwise_fma(P, W, (f32x2){0.00021858087f, 0.00021858087f});
    P = __builtin_elementwise_fma(P, W, (f32x2){-0.00125372503f, -0.00125372503f});
    P = __builtin_elementwise_fma(P, W, (f32x2){-0.00417768164f, -0.00417768164f});
    P = __builtin_elementwise_fma(P, W, (f32x2){0.246640727f, 0.246640727f});
    P = __builtin_elementwise_fma(P, W, (f32x2){1.50140941f, 1.50140941f});
    f32x2 Q = (P * X) * (f32x2){0.14142135f, 0.14142135f};  // 0.1*sqrt(2)
    z = fmaf(0.95f, z, Q.x);
    z = fmaf(0.95f, z, Q.y);
  }
  Z[j] = f2bf(z);
}

// ---------------------------------------------------------------------------
// GEMM tile (bf16 A): Out[128x128 tile] = bf16(relu(A @ WT^T + bias)).
// ---------------------------------------------------------------------------
__device__ __forceinline__ void gemm_tile_bf(
    const ushort* __restrict__ A, const ushort* __restrict__ WT,
    const float* __restrict__ bias, ushort* __restrict__ Out, int g,
    ushort As[128][40], ushort Bs[128][40]) {
  const int n0 = (g & 7) * 128, m0 = (g >> 3) * 128;
  const int t = threadIdx.x;
  const int srow = t >> 1, skb = (t & 1) << 4;
  const ushort* Ap = A  + (size_t)(m0 + srow) * Dn + skb;
  const ushort* Bp = WT + (size_t)(n0 + srow) * Dn + skb;
  const int wave = t >> 6, lane = t & 63;
  const int wm = (wave >> 1) << 6, wn = (wave & 1) << 6;
  const int quad = lane >> 4, l15 = lane & 15;

  f32x4 acc[4][4] = {};
  for (int k0 = 0; k0 < Dn; k0 += 32) {
    uint4 a0 = *(const uint4*)(Ap + k0);
    uint4 a1 = *(const uint4*)(Ap + k0 + 8);
    uint4 b0 = *(const uint4*)(Bp + k0);
    uint4 b1 = *(const uint4*)(Bp + k0 + 8);
    *(uint4*)&As[srow][skb] = a0; *(uint4*)&As[srow][skb + 8] = a1;
    *(uint4*)&Bs[srow][skb] = b0; *(uint4*)&Bs[srow][skb + 8] = b1;
    __syncthreads();
    bf16x8 af[4], bfr[4];
#pragma unroll
    for (int i = 0; i < 4; ++i) {
      af[i] = *(const bf16x8*)&As[wm + i * 16 + l15][quad * 8];
      bfr[i] = *(const bf16x8*)&Bs[wn + i * 16 + l15][quad * 8];
    }
#pragma unroll
    for (int i = 0; i < 4; ++i)
#pragma unroll
      for (int j = 0; j < 4; ++j)
        acc[i][j] = __builtin_amdgcn_mfma_f32_16x16x32_bf16(af[i], bfr[j],
                                                            acc[i][j], 0, 0, 0);
    __syncthreads();
  }
#pragma unroll
  for (int i = 0; i < 4; ++i)
#pragma unroll
    for (int j = 0; j < 4; ++j) {
      const int col = n0 + wn + j * 16 + l15;
      const float bv = bias[col];
#pragma unroll
      for (int r = 0; r < 4; ++r) {
        const int row = m0 + wm + i * 16 + quad * 4 + r;
        Out[(size_t)row * Hn + col] = f2bf(fmaxf(acc[i][j][r] + bv, 0.0f));
      }
    }
}

// K1: 34816 blocks = 1024 groups x 34: pos 0=G1, 1=G3, 2..33=Zdyn
__global__ __launch_bounds__(256) void k_mega2(
    const ushort* __restrict__ x_bf,
    const ushort* __restrict__ W1eT, const float* __restrict__ b1e,
    ushort* __restrict__ h,
    const ushort* __restrict__ W1rT, const float* __restrict__ b1r,
    ushort* __restrict__ hr,
    ushort* __restrict__ Zdyn) {
  __shared__ ushort As[128][40];
  __shared__ ushort Bs[128][40];
  const uint32_t bx = blockIdx.x;
  const uint32_t group = bx / 34u, pos = bx % 34u;
  if (pos == 0u)
    gemm_tile_bf(x_bf, W1eT, b1e, h, (int)group, As, Bs);
  else if (pos == 1u)
    gemm_tile_bf(x_bf, W1rT, b1r, hr, (int)group, As, Bs);
  else
    zdyn_block(Zdyn, group * 32u + (pos - 2u));
}

// ---------------------------------------------------------------------------
// Conversions
// ---------------------------------------------------------------------------
__global__ __launch_bounds__(256) void k_cvt_x(const float* __restrict__ in,
                                               ushort* __restrict__ out) {
  int i = (blockIdx.x * 256 + threadIdx.x) * 4;
  float4 v = *(const float4*)(in + i);
  *(ushort4*)(out + i) = make_ushort4(f2bf(v.x), f2bf(v.y), f2bf(v.z), f2bf(v.w));
}

__global__ __launch_bounds__(256) void k_transpose_cvt(
    const float* __restrict__ in, ushort* __restrict__ out, int NO, int KO) {
  int o = blockIdx.x * 256 + threadIdx.x;
  int n = o / KO, k = o % KO;
  out[o] = f2bf(in[(size_t)k * NO + n]);
}

// ---------------------------------------------------------------------------
// K2: double GEMM + gate (verified round 7/8).
// ---------------------------------------------------------------------------
__global__ __launch_bounds__(256) void k_dgemm(
    const ushort* __restrict__ h, const ushort* __restrict__ W2eT,
    const float* __restrict__ b2e,
    const ushort* __restrict__ hr, const ushort* __restrict__ W2rT,
    const float* __restrict__ b2r,
    ushort* __restrict__ Zconc) {
  __shared__ ushort As[128][40];
  __shared__ ushort Bs[128][40];
  const int t = threadIdx.x;
  const int m0 = blockIdx.y * 128, n0 = blockIdx.x * 128;
  const int srow = t >> 1, skb = (t & 1) << 4;
  const int wave = t >> 6, lane = t & 63;
  const int wm = (wave >> 1) << 6, wn = (wave & 1) << 6;
  const int quad = lane >> 4, l15 = lane & 15;

  const ushort* Ap = h    + (size_t)(m0 + srow) * Hn + skb;
  const ushort* Bp = W2eT + (size_t)(n0 + srow) * Hn + skb;
  f32x4 acc[4][4] = {};
  for (int k0 = 0; k0 < Hn; k0 += 32) {
    uint4 a0 = *(const uint4*)(Ap + k0);
    uint4 a1 = *(const uint4*)(Ap + k0 + 8);
    uint4 b0 = *(const uint4*)(Bp + k0);
    uint4 b1 = *(const uint4*)(Bp + k0 + 8);
    *(uint4*)&As[srow][skb] = a0; *(uint4*)&As[srow][skb + 8] = a1;
    *(uint4*)&Bs[srow][skb] = b0; *(uint4*)&Bs[srow][skb + 8] = b1;
    __syncthreads();
    bf16x8 af[4], bfr[4];
#pragma unroll
    for (int i = 0; i < 4; ++i) {
      af[i] = *(const bf16x8*)&As[wm + i * 16 + l15][quad * 8];
      bfr[i] = *(const bf16x8*)&Bs[wn + i * 16 + l15][quad * 8];
    }
#pragma unroll
    for (int i = 0; i < 4; ++i)
#pragma unroll
      for (int j = 0; j < 4; ++j)
        acc[i][j] = __builtin_amdgcn_mfma_f32_16x16x32_bf16(af[i], bfr[j],
                                                            acc[i][j], 0, 0, 0);
    __syncthreads();
  }
  float g[4][4][4];
#pragma unroll
  for (int i = 0; i < 4; ++i)
#pragma unroll
    for (int j = 0; j < 4; ++j) {
      const int col = n0 + wn + j * 16 + l15;
      const float bv = b2e[col];
#pragma unroll
      for (int r = 0; r < 4; ++r) {
        const int row = m0 + wm + i * 16 + quad * 4 + r;
        float e = acc[i][j][r] + bv;
        float z = b2f(Zconc[(size_t)row * Cn + col]);
        g[i][j][r] = 1.0f / (1.0f + __expf(z - A32 * e));
        acc[i][j][r] = 0.0f;
      }
    }
  Ap = hr   + (size_t)(m0 + srow) * Hn + skb;
  Bp = W2rT + (size_t)(n0 + srow) * Hn + skb;
  for (int k0 = 0; k0 < Hn; k0 += 32) {
    uint4 a0 = *(const uint4*)(Ap + k0);
    uint4 a1 = *(const uint4*)(Ap + k0 + 8);
    uint4 b0 = *(const uint4*)(Bp + k0);
    uint4 b1 = *(const uint4*)(Bp + k0 + 8);
    __syncthreads();
    *(uint4*)&As[srow][skb] = a0; *(uint4*)&As[srow][skb + 8] = a1;
    *(uint4*)&Bs[srow][skb] = b0; *(uint4*)&Bs[srow][skb + 8] = b1;
    __syncthreads();
    bf16x8 af[4], bfr[4];
#pragma unroll
    for (int i = 0; i < 4; ++i) {
      af[i] = *(const bf16x8*)&As[wm + i * 16 + l15][quad * 8];
      bfr[i] = *(const bf16x8*)&Bs[wn + i * 16 + l15][quad * 8];
    }
#pragma unroll
    for (int i = 0; i < 4; ++i)
#pragma unroll
      for (int j = 0; j < 4; ++j)
        acc[i][j] = __builtin_amdgcn_mfma_f32_16x16x32_bf16(af[i], bfr[j],
                                                            acc[i][j], 0, 0, 0);
  }
#pragma unroll
  for (int i = 0; i < 4; ++i)
#pragma unroll
    for (int j = 0; j < 4; ++j) {
      const int col = n0 + wn + j * 16 + l15;
      const float bv = b2r[col];
#pragma unroll
      for (int r = 0; r < 4; ++r) {
        const int row = m0 + wm + i * 16 + quad * 4 + r;
        Zconc[(size_t)row * Cn + col] = f2bf((acc[i][j][r] + bv) * g[i][j][r]);
      }
    }
}

// ---------------------------------------------------------------------------
// K3: out = conc @ comps
// ---------------------------------------------------------------------------
__global__ __launch_bounds__(256) void k_gemm_out(
    const ushort* __restrict__ A, const ushort* __restrict__ WT,
    float* __restrict__ Out) {
  __shared__ ushort As[128][40];
  __shared__ ushort Bs[128][40];
  const int t = threadIdx.x;
  const int m0 = blockIdx.y * 128, n0 = blockIdx.x * 128;
  const int srow = t >> 1, skb = (t & 1) << 4;
  const ushort* Ap = A  + (size_t)(m0 + srow) * Cn + skb;
  const ushort* Bp = WT + (size_t)(n0 + srow) * Cn + skb;
  const int wave = t >> 6, lane = t & 63;
  const int wm = (wave >> 1) << 6, wn = (wave & 1) << 6;
  const int quad = lane >> 4, l15 = lane & 15;

  f32x4 acc[4][4] = {};
  for (int k0 = 0; k0 < Cn; k0 += 32) {
    uint4 a0 = *(const uint4*)(Ap + k0);
    uint4 a1 = *(const uint4*)(Ap + k0 + 8);
    uint4 b0 = *(const uint4*)(Bp + k0);
    uint4 b1 = *(const uint4*)(Bp + k0 + 8);
    *(uint4*)&As[srow][skb] = a0; *(uint4*)&As[srow][skb + 8] = a1;
    *(uint4*)&Bs[srow][skb] = b0; *(uint4*)&Bs[srow][skb + 8] = b1;
    __syncthreads();
    bf16x8 af[4], bfr[4];
#pragma unroll
    for (int i = 0; i < 4; ++i) {
      af[i] = *(const bf16x8*)&As[wm + i * 16 + l15][quad * 8];
      bfr[i] = *(const bf16x8*)&Bs[wn + i * 16 + l15][quad * 8];
    }
#pragma unroll
    for (int i = 0; i < 4; ++i)
#pragma unroll
      for (int j = 0; j < 4; ++j)
        acc[i][j] = __builtin_amdgcn_mfma_f32_16x16x32_bf16(af[i], bfr[j],
                                                            acc[i][j], 0, 0, 0);
    __syncthreads();
  }
#pragma unroll
  for (int i = 0; i < 4; ++i)
#pragma unroll
    for (int j = 0; j < 4; ++j) {
      const int col = n0 + wn + j * 16 + l15;
#pragma unroll
      for (int r = 0; r < 4; ++r) {
        const int row = m0 + wm + i * 16 + quad * 4 + r;
        Out[(size_t)row * Dn + col] = acc[i][j][r];
      }
    }
}

// ---------------------------------------------------------------------------
extern "C" void kernel_launch(void* const* d_in, const int* in_sizes, int n_in,
                              void* d_out, int out_size, void* d_ws, size_t ws_size,
                              hipStream_t stream) {
  const float* x    = (const float*)d_in[0];
  const float* vc   = (const float*)d_in[1];
  const float* e_sp = (const float*)d_in[2];
  const float* W1e  = (const float*)d_in[3];
  const float* b1e  = (const float*)d_in[4];
  const float* W2e  = (const float*)d_in[5];
  const float* b2e  = (const float*)d_in[6];
  const float* W1r  = (const float*)d_in[7];
  const float* b1r  = (const float*)d_in[8];
  const float* W2r  = (const float*)d_in[9];
  const float* b2r  = (const float*)d_in[10];
  float* out = (float*)d_out;

  // Workspace (88 MiB high-water):
  //   4096    W1eT | +1M W2eT | +2M W1rT | +3M W2rT  (bf16 transposed)
  //   +4M     compsT [D][C] bf16 (0.5 MiB)
  //   8M      Zdyn [B][C] bf16 (16 MiB) -> aliased as conc after K2
  //   24M     h  [B][H] bf16 (32 MiB)
  //   56M     hr [B][H] bf16 (32 MiB)
  // x_bf (16 MiB) lives in d_out (32 MiB, dead until K3 overwrites it).
  char* ws = (char*)d_ws;
  ushort* W1eT   = (ushort*)(ws + (1u << 12));
  ushort* W2eT   = (ushort*)(ws + (1u << 12) + (1u << 20));
  ushort* W1rT   = (ushort*)(ws + (1u << 12) + (2u << 20));
  ushort* W2rT   = (ushort*)(ws + (1u << 12) + (3u << 20));
  ushort* compsT = (ushort*)(ws + (1u << 12) + (4u << 20));
  ushort* Zdyn   = (ushort*)(ws + (8u << 20));   // then conc
  ushort* h_bf   = (ushort*)(ws + (24u << 20));
  ushort* hr_bf  = (ushort*)(ws + (56u << 20));
  ushort* x_bf   = (ushort*)d_out;               // scratch until K3

  // 1. conversions (keys are compile-time constants now — no setup kernel)
  k_cvt_x<<<(Bn * Dn / 4) / 256, 256, 0, stream>>>(x, x_bf);
  k_transpose_cvt<<<(Dn * Hn) / 256, 256, 0, stream>>>(W1e, W1eT, Hn, Dn);
  k_transpose_cvt<<<(Hn * Cn) / 256, 256, 0, stream>>>(W2e, W2eT, Cn, Hn);
  k_transpose_cvt<<<(Dn * Hn) / 256, 256, 0, stream>>>(W1r, W1rT, Hn, Dn);
  k_transpose_cvt<<<(Hn * Cn) / 256, 256, 0, stream>>>(W2r, W2rT, Cn, Hn);
  // 2. static mask (standalone, full unroll, literal keys)
  k_smask<<<(Cn * Dn) / 256, 256, 0, stream>>>(vc, e_sp, compsT);
  // 3. mega: G1(h) + G3(hr) + Zdyn co-scheduled
  k_mega2<<<34816, 256, 0, stream>>>(x_bf, W1eT, b1e, h_bf, W1rT, b1r, hr_bf,
                                     Zdyn);
  // 4. double GEMM: e -> gate -> conc (in-place over Zdyn)
  k_dgemm<<<dim3(Cn / 128, Bn / 128), 256, 0, stream>>>(
      h_bf, W2eT, b2e, hr_bf, W2rT, b2r, Zdyn);
  // 5. out = conc @ comps
  k_gemm_out<<<dim3(Dn / 128, Bn / 128), 256, 0, stream>>>(Zdyn, compsT, out);
}

// Round 10
// 835.112 us; speedup vs baseline: 1.0524x; 1.0524x over previous
//
#include <hip/hip_runtime.h>
#include <hip/hip_bf16.h>
#include <stdint.h>

// Problem dims
#define Bn 16384
#define Cn 512
#define Dn 512
#define Hn 1024

// a = 1 - 0.95^32 (closed-form Langevin: u32 = -a*e + Z)
#define A32 0.80628851f

typedef __attribute__((ext_vector_type(8))) short bf16x8;   // 8 bf16 (4 VGPRs)
typedef __attribute__((ext_vector_type(4))) float f32x4;    // MFMA accum
typedef __attribute__((ext_vector_type(2))) float f32x2;    // packed fp32 pair

// f32 -> bf16 RTNE (manual; inputs are finite)
__device__ __forceinline__ ushort f2bf(float f) {
  uint32_t u = __float_as_uint(f);
  return (ushort)((u + 0x7fffu + ((u >> 16) & 1u)) >> 16);
}
__device__ __forceinline__ float b2f(ushort u) {
  return __uint_as_float((uint32_t)u << 16);
}

// ---------------------------------------------------------------------------
// COMPILE-TIME threefry2x32 key schedule (partitionable JAX, verified round 4)
// ---------------------------------------------------------------------------
constexpr uint32_t crotl(uint32_t v, int s) {
  return (v << s) | (v >> (32 - s));
}
struct TFOut { uint32_t w0, w1; };
constexpr TFOut ctf(uint32_t k0, uint32_t k1, uint32_t x0, uint32_t x1) {
  const uint32_t ks[3] = {k0, k1, k0 ^ k1 ^ 0x1BD11BDAu};
  const int rot[8] = {13, 15, 26, 6, 17, 29, 16, 24};
  uint32_t a = x0 + k0, b = x1 + k1;
  for (int g = 0; g < 5; ++g) {
    for (int i = 0; i < 4; ++i) {
      int r = rot[(g & 1) * 4 + i];
      a += b; b = crotl(b, r); b ^= a;
    }
    a += ks[(g + 1) % 3];
    b += ks[(g + 2) % 3] + (uint32_t)(g + 1);
  }
  return {a, b};
}
struct KeySched { uint32_t s[64]; uint32_t d[64]; };
constexpr KeySched make_keys() {
  KeySched K{};
  TFOut k1 = ctf(0u, 42u, 0u, 0u);  // split(key(42))[0]
  TFOut k2 = ctf(0u, 42u, 0u, 1u);  // split(key(42))[1]
  for (uint32_t t = 0; t < 32; ++t) {
    TFOut ws = ctf(k1.w0, k1.w1, 0u, t);
    K.s[2 * t] = ws.w0; K.s[2 * t + 1] = ws.w1;
    TFOut wd = ctf(k2.w0, k2.w1, 0u, t);
    K.d[2 * t] = wd.w0; K.d[2 * t + 1] = wd.w1;
  }
  return K;
}
constexpr KeySched KS = make_keys();

__device__ __forceinline__ uint32_t rotl32(uint32_t v, int s) {
  return __builtin_rotateleft32(v, (uint32_t)s);
}
__device__ __forceinline__ uint32_t tf_xor(uint32_t K0, uint32_t K1,
                                           uint32_t KX, uint32_t j) {
  uint32_t a = K0, b = K1 + j;
#define TR(r) { a += b; b = rotl32(b, (r)); b ^= a; }
  TR(13) TR(15) TR(26) TR(6)   a += K1; b += KX + 1u;
  TR(17) TR(29) TR(16) TR(24)  a += KX; b += K0 + 2u;
  TR(13) TR(15) TR(26) TR(6)   a += K0; b += K1 + 3u;
  TR(17) TR(29) TR(16) TR(24)  a += K1; b += KX + 4u;
  TR(13) TR(15) TR(26) TR(6)   a += KX; b += K0 + 5u;
#undef TR
  return a ^ b;
}

// Exact (branchy) bits->normal — static-mask path (verified).
__device__ __forceinline__ float bits_to_normal(uint32_t bits) {
  float f = __uint_as_float((bits >> 9) | 0x3f800000u) - 1.0f;
  float x = f * 2.0f - 0x1.fffffep-1f;
  float w = -__logf(1.0f - x * x);
  float p;
  if (w < 5.0f) {
    w -= 2.5f;
    p =            2.81022636e-08f;
    p = fmaf(p, w, 3.43273939e-07f);
    p = fmaf(p, w, -3.5233877e-06f);
    p = fmaf(p, w, -4.39150654e-06f);
    p = fmaf(p, w, 0.00021858087f);
    p = fmaf(p, w, -0.00125372503f);
    p = fmaf(p, w, -0.00417768164f);
    p = fmaf(p, w, 0.246640727f);
    p = fmaf(p, w, 1.50140941f);
  } else {
    w = sqrtf(w) - 3.0f;
    p =            -0.000200214257f;
    p = fmaf(p, w, 0.000100950558f);
    p = fmaf(p, w, 0.00134934322f);
    p = fmaf(p, w, -0.00367342844f);
    p = fmaf(p, w, 0.00573950773f);
    p = fmaf(p, w, -0.0076224613f);
    p = fmaf(p, w, 0.00943887047f);
    p = fmaf(p, w, 1.00167406f);
    p = fmaf(p, w, 2.83297682f);
  }
  return 0x1.6a09e6p+0f * (p * x);
}

// ---------------------------------------------------------------------------
// Z: standalone, 2 elems/thread, manual 2-chain interleave, literal keys,
// full unroll, packed f32x2 tails.  Bit-identical per-element to rounds 8/9.
// ---------------------------------------------------------------------------
__global__ __launch_bounds__(256) void k_z(ushort* __restrict__ Z) {
  const uint32_t j0 = (blockIdx.x * 256u + threadIdx.x) * 2u;
  const uint32_t j1 = j0 + 1u;
  float z0 = 0.0f, z1 = 0.0f;
#pragma unroll
  for (int t = 0; t < 32; ++t) {
    const uint32_t K0 = KS.d[2 * t], K1 = KS.d[2 * t + 1];
    const uint32_t KX = K0 ^ K1 ^ 0x1BD11BDAu;
    uint32_t a0 = K0, b0 = K1 + j0;
    uint32_t a1 = K0, b1 = K1 + j1;
#define R2(r)                                                  \
    a0 += b0; a1 += b1;                                        \
    b0 = rotl32(b0, (r)); b1 = rotl32(b1, (r));                \
    b0 ^= a0; b1 ^= a1;
#define I2(p, q) a0 += (p); a1 += (p); b0 += (q); b1 += (q);
    R2(13) R2(15) R2(26) R2(6)  I2(K1, KX + 1u)
    R2(17) R2(29) R2(16) R2(24) I2(KX, K0 + 2u)
    R2(13) R2(15) R2(26) R2(6)  I2(K0, K1 + 3u)
    R2(17) R2(29) R2(16) R2(24) I2(K1, KX + 4u)
    R2(13) R2(15) R2(26) R2(6)  I2(KX, K0 + 5u)
#undef R2
#undef I2
    uint32_t s0 = a0 ^ b0, s1 = a1 ^ b1;
    float f0 = __uint_as_float((s0 >> 9) | 0x3f800000u) - 1.0f;
    float f1 = __uint_as_float((s1 >> 9) | 0x3f800000u) - 1.0f;
    float x0 = f0 * 2.0f - 0x1.fffffep-1f;
    float x1 = f1 * 2.0f - 0x1.fffffep-1f;
    float w0 = fminf(-__logf(fmaf(-x0, x0, 1.0f)), 5.0f) - 2.5f;
    float w1 = fminf(-__logf(fmaf(-x1, x1, 1.0f)), 5.0f) - 2.5f;
    f32x2 X = {x0, x1}, W = {w0, w1};
    f32x2 P = {2.81022636e-08f, 2.81022636e-08f};
    P = __builtin_elementwise_fma(P, W, (f32x2){3.43273939e-07f, 3.43273939e-07f});
    P = __builtin_elementwise_fma(P, W, (f32x2){-3.5233877e-06f, -3.5233877e-06f});
    P = __builtin_elementwise_fma(P, W, (f32x2){-4.39150654e-06f, -4.39150654e-06f});
    P = __builtin_elementwise_fma(P, W, (f32x2){0.00021858087f, 0.00021858087f});
    P = __builtin_elementwise_fma(P, W, (f32x2){-0.00125372503f, -0.00125372503f});
    P = __builtin_elementwise_fma(P, W, (f32x2){-0.00417768164f, -0.00417768164f});
    P = __builtin_elementwise_fma(P, W, (f32x2){0.246640727f, 0.246640727f});
    P = __builtin_elementwise_fma(P, W, (f32x2){1.50140941f, 1.50140941f});
    f32x2 Q = (P * X) * (f32x2){0.14142135f, 0.14142135f};  // 0.1*sqrt(2)
    z0 = fmaf(0.95f, z0, Q.x);
    z1 = fmaf(0.95f, z1, Q.y);
  }
  *(ushort2*)(Z + j0) = make_ushort2(f2bf(z0), f2bf(z1));
}

// ---------------------------------------------------------------------------
// PREP hetero kernel: cvt_x + 4 LDS-tiled coalesced transposes + smask.
// Grid: [0,8192) cvt_x | 4x512 transpose tiles | [10240,11264) smask
// ---------------------------------------------------------------------------
__device__ __forceinline__ void transpose_tile(
    const float* __restrict__ in, ushort* __restrict__ out,
    int N, int K, int tIdx, float T[32][33]) {
  const int ntn = N / 32;
  const int tk = tIdx / ntn, tn = tIdx % ntn;
  const int tx = threadIdx.x & 31, ty = threadIdx.x >> 5;  // 32 x 8
  const int k0 = tk * 32, n0 = tn * 32;
#pragma unroll
  for (int r = 0; r < 32; r += 8)
    T[ty + r][tx] = in[(size_t)(k0 + ty + r) * N + n0 + tx];
  __syncthreads();
#pragma unroll
  for (int r = 0; r < 32; r += 8)
    out[(size_t)(n0 + ty + r) * K + k0 + tx] = f2bf(T[tx][ty + r]);
}

__device__ __forceinline__ void smask_block(
    const float* __restrict__ vc, const float* __restrict__ e_sp,
    ushort* __restrict__ compsT, int g) {
  uint32_t jj = (uint32_t)g * 256 + threadIdx.x;  // j = d*C + c
  uint32_t c = jj & (Cn - 1), d = jj >> 9;
  uint32_t ridx = c * Dn + d;
  float e = e_sp[ridx];
  float u = 0.0f;
#pragma unroll
  for (int t = 0; t < 32; ++t) {
    const uint32_t K0 = KS.s[2 * t], K1 = KS.s[2 * t + 1];
    uint32_t s = tf_xor(K0, K1, K0 ^ K1 ^ 0x1BD11BDAu, ridx);
    float n = bits_to_normal(s);
    u = (u - 0.05f * (u + e)) + 0.1f * n;
  }
  float gt = 1.0f / (1.0f + __expf(u));
  compsT[jj] = f2bf(fabsf(vc[ridx]) * gt);
}

__global__ __launch_bounds__(256) void k_prep(
    const float* __restrict__ x, ushort* __restrict__ x_bf,
    const float* __restrict__ W1e, ushort* __restrict__ W1eT,
    const float* __restrict__ W2e, ushort* __restrict__ W2eT,
    const float* __restrict__ W1r, ushort* __restrict__ W1rT,
    const float* __restrict__ W2r, ushort* __restrict__ W2rT,
    const float* __restrict__ vc, const float* __restrict__ e_sp,
    ushort* __restrict__ compsT) {
  __shared__ float T[32][33];
  const int pos = blockIdx.x;
  if (pos < 8192) {
    int i = (pos * 256 + threadIdx.x) * 4;
    float4 v = *(const float4*)(x + i);
    *(ushort4*)(x_bf + i) =
        make_ushort4(f2bf(v.x), f2bf(v.y), f2bf(v.z), f2bf(v.w));
  } else if (pos < 8704) {
    transpose_tile(W1e, W1eT, Hn, Dn, pos - 8192, T);   // [D][H] -> [H][D]
  } else if (pos < 9216) {
    transpose_tile(W2e, W2eT, Cn, Hn, pos - 8704, T);   // [H][C] -> [C][H]
  } else if (pos < 9728) {
    transpose_tile(W1r, W1rT, Hn, Dn, pos - 9216, T);
  } else if (pos < 10240) {
    transpose_tile(W2r, W2rT, Cn, Hn, pos - 9728, T);
  } else {
    smask_block(vc, e_sp, compsT, pos - 10240);
  }
}

// ---------------------------------------------------------------------------
// GEMM tile (bf16): Out[128x128 tile] = bf16(relu(A @ WT^T + bias))
// ---------------------------------------------------------------------------
__device__ __forceinline__ void gemm_tile_bf(
    const ushort* __restrict__ A, const ushort* __restrict__ WT,
    const float* __restrict__ bias, ushort* __restrict__ Out, int g,
    ushort As[128][40], ushort Bs[128][40]) {
  const int n0 = (g & 7) * 128, m0 = (g >> 3) * 128;
  const int t = threadIdx.x;
  const int srow = t >> 1, skb = (t & 1) << 4;
  const ushort* Ap = A  + (size_t)(m0 + srow) * Dn + skb;
  const ushort* Bp = WT + (size_t)(n0 + srow) * Dn + skb;
  const int wave = t >> 6, lane = t & 63;
  const int wm = (wave >> 1) << 6, wn = (wave & 1) << 6;
  const int quad = lane >> 4, l15 = lane & 15;

  f32x4 acc[4][4] = {};
  for (int k0 = 0; k0 < Dn; k0 += 32) {
    uint4 a0 = *(const uint4*)(Ap + k0);
    uint4 a1 = *(const uint4*)(Ap + k0 + 8);
    uint4 b0 = *(const uint4*)(Bp + k0);
    uint4 b1 = *(const uint4*)(Bp + k0 + 8);
    *(uint4*)&As[srow][skb] = a0; *(uint4*)&As[srow][skb + 8] = a1;
    *(uint4*)&Bs[srow][skb] = b0; *(uint4*)&Bs[srow][skb + 8] = b1;
    __syncthreads();
    bf16x8 af[4], bfr[4];
#pragma unroll
    for (int i = 0; i < 4; ++i) {
      af[i] = *(const bf16x8*)&As[wm + i * 16 + l15][quad * 8];
      bfr[i] = *(const bf16x8*)&Bs[wn + i * 16 + l15][quad * 8];
    }
#pragma unroll
    for (int i = 0; i < 4; ++i)
#pragma unroll
      for (int j = 0; j < 4; ++j)
        acc[i][j] = __builtin_amdgcn_mfma_f32_16x16x32_bf16(af[i], bfr[j],
                                                            acc[i][j], 0, 0, 0);
    __syncthreads();
  }
#pragma unroll
  for (int i = 0; i < 4; ++i)
#pragma unroll
    for (int j = 0; j < 4; ++j) {
      const int col = n0 + wn + j * 16 + l15;
      const float bv = bias[col];
#pragma unroll
      for (int r = 0; r < 4; ++r) {
        const int row = m0 + wm + i * 16 + quad * 4 + r;
        Out[(size_t)row * Hn + col] = f2bf(fmaxf(acc[i][j][r] + bv, 0.0f));
      }
    }
}

// G1 + G3: 2048 tiles (even = e-MLP, odd = r-MLP)
__global__ __launch_bounds__(256) void k_g13(
    const ushort* __restrict__ x_bf,
    const ushort* __restrict__ W1eT, const float* __restrict__ b1e,
    ushort* __restrict__ h,
    const ushort* __restrict__ W1rT, const float* __restrict__ b1r,
    ushort* __restrict__ hr) {
  __shared__ ushort As[128][40];
  __shared__ ushort Bs[128][40];
  const int pos = blockIdx.x;
  const int g = pos >> 1;
  if (pos & 1)
    gemm_tile_bf(x_bf, W1rT, b1r, hr, g, As, Bs);
  else
    gemm_tile_bf(x_bf, W1eT, b1e, h, g, As, Bs);
}

// ---------------------------------------------------------------------------
// K2: double GEMM + gate (verified rounds 7-9)
// ---------------------------------------------------------------------------
__global__ __launch_bounds__(256) void k_dgemm(
    const ushort* __restrict__ h, const ushort* __restrict__ W2eT,
    const float* __restrict__ b2e,
    const ushort* __restrict__ hr, const ushort* __restrict__ W2rT,
    const float* __restrict__ b2r,
    ushort* __restrict__ Zconc) {
  __shared__ ushort As[128][40];
  __shared__ ushort Bs[128][40];
  const int t = threadIdx.x;
  const int m0 = blockIdx.y * 128, n0 = blockIdx.x * 128;
  const int srow = t >> 1, skb = (t & 1) << 4;
  const int wave = t >> 6, lane = t & 63;
  const int wm = (wave >> 1) << 6, wn = (wave & 1) << 6;
  const int quad = lane >> 4, l15 = lane & 15;

  const ushort* Ap = h    + (size_t)(m0 + srow) * Hn + skb;
  const ushort* Bp = W2eT + (size_t)(n0 + srow) * Hn + skb;
  f32x4 acc[4][4] = {};
  for (int k0 = 0; k0 < Hn; k0 += 32) {
    uint4 a0 = *(const uint4*)(Ap + k0);
    uint4 a1 = *(const uint4*)(Ap + k0 + 8);
    uint4 b0 = *(const uint4*)(Bp + k0);
    uint4 b1 = *(const uint4*)(Bp + k0 + 8);
    *(uint4*)&As[srow][skb] = a0; *(uint4*)&As[srow][skb + 8] = a1;
    *(uint4*)&Bs[srow][skb] = b0; *(uint4*)&Bs[srow][skb + 8] = b1;
    __syncthreads();
    bf16x8 af[4], bfr[4];
#pragma unroll
    for (int i = 0; i < 4; ++i) {
      af[i] = *(const bf16x8*)&As[wm + i * 16 + l15][quad * 8];
      bfr[i] = *(const bf16x8*)&Bs[wn + i * 16 + l15][quad * 8];
    }
#pragma unroll
    for (int i = 0; i < 4; ++i)
#pragma unroll
      for (int j = 0; j < 4; ++j)
        acc[i][j] = __builtin_amdgcn_mfma_f32_16x16x32_bf16(af[i], bfr[j],
                                                            acc[i][j], 0, 0, 0);
    __syncthreads();
  }
  float g[4][4][4];
#pragma unroll
  for (int i = 0; i < 4; ++i)
#pragma unroll
    for (int j = 0; j < 4; ++j) {
      const int col = n0 + wn + j * 16 + l15;
      const float bv = b2e[col];
#pragma unroll
      for (int r = 0; r < 4; ++r) {
        const int row = m0 + wm + i * 16 + quad * 4 + r;
        float e = acc[i][j][r] + bv;
        float z = b2f(Zconc[(size_t)row * Cn + col]);
        g[i][j][r] = 1.0f / (1.0f + __expf(z - A32 * e));
        acc[i][j][r] = 0.0f;
      }
    }
  Ap = hr   + (size_t)(m0 + srow) * Hn + skb;
  Bp = W2rT + (size_t)(n0 + srow) * Hn + skb;
  for (int k0 = 0; k0 < Hn; k0 += 32) {
    uint4 a0 = *(const uint4*)(Ap + k0);
    uint4 a1 = *(const uint4*)(Ap + k0 + 8);
    uint4 b0 = *(const uint4*)(Bp + k0);
    uint4 b1 = *(const uint4*)(Bp + k0 + 8);
    __syncthreads();
    *(uint4*)&As[srow][skb] = a0; *(uint4*)&As[srow][skb + 8] = a1;
    *(uint4*)&Bs[srow][skb] = b0; *(uint4*)&Bs[srow][skb + 8] = b1;
    __syncthreads();
    bf16x8 af[4], bfr[4];
#pragma unroll
    for (int i = 0; i < 4; ++i) {
      af[i] = *(const bf16x8*)&As[wm + i * 16 + l15][quad * 8];
      bfr[i] = *(const bf16x8*)&Bs[wn + i * 16 + l15][quad * 8];
    }
#pragma unroll
    for (int i = 0; i < 4; ++i)
#pragma unroll
      for (int j = 0; j < 4; ++j)
        acc[i][j] = __builtin_amdgcn_mfma_f32_16x16x32_bf16(af[i], bfr[j],
                                                            acc[i][j], 0, 0, 0);
  }
#pragma unroll
  for (int i = 0; i < 4; ++i)
#pragma unroll
    for (int j = 0; j < 4; ++j) {
      const int col = n0 + wn + j * 16 + l15;
      const float bv = b2r[col];
#pragma unroll
      for (int r = 0; r < 4; ++r) {
        const int row = m0 + wm + i * 16 + quad * 4 + r;
        Zconc[(size_t)row * Cn + col] = f2bf((acc[i][j][r] + bv) * g[i][j][r]);
      }
    }
}

// ---------------------------------------------------------------------------
// K3: out = conc @ comps
// ---------------------------------------------------------------------------
__global__ __launch_bounds__(256) void k_gemm_out(
    const ushort* __restrict__ A, const ushort* __restrict__ WT,
    float* __restrict__ Out) {
  __shared__ ushort As[128][40];
  __shared__ ushort Bs[128][40];
  const int t = threadIdx.x;
  const int m0 = blockIdx.y * 128, n0 = blockIdx.x * 128;
  const int srow = t >> 1, skb = (t & 1) << 4;
  const ushort* Ap = A  + (size_t)(m0 + srow) * Cn + skb;
  const ushort* Bp = WT + (size_t)(n0 + srow) * Cn + skb;
  const int wave = t >> 6, lane = t & 63;
  const int wm = (wave >> 1) << 6, wn = (wave & 1) << 6;
  const int quad = lane >> 4, l15 = lane & 15;

  f32x4 acc[4][4] = {};
  for (int k0 = 0; k0 < Cn; k0 += 32) {
    uint4 a0 = *(const uint4*)(Ap + k0);
    uint4 a1 = *(const uint4*)(Ap + k0 + 8);
    uint4 b0 = *(const uint4*)(Bp + k0);
    uint4 b1 = *(const uint4*)(Bp + k0 + 8);
    *(uint4*)&As[srow][skb] = a0; *(uint4*)&As[srow][skb + 8] = a1;
    *(uint4*)&Bs[srow][skb] = b0; *(uint4*)&Bs[srow][skb + 8] = b1;
    __syncthreads();
    bf16x8 af[4], bfr[4];
#pragma unroll
    for (int i = 0; i < 4; ++i) {
      af[i] = *(const bf16x8*)&As[wm + i * 16 + l15][quad * 8];
      bfr[i] = *(const bf16x8*)&Bs[wn + i * 16 + l15][quad * 8];
    }
#pragma unroll
    for (int i = 0; i < 4; ++i)
#pragma unroll
      for (int j = 0; j < 4; ++j)
        acc[i][j] = __builtin_amdgcn_mfma_f32_16x16x32_bf16(af[i], bfr[j],
                                                            acc[i][j], 0, 0, 0);
    __syncthreads();
  }
#pragma unroll
  for (int i = 0; i < 4; ++i)
#pragma unroll
    for (int j = 0; j < 4; ++j) {
      const int col = n0 + wn + j * 16 + l15;
#pragma unroll
      for (int r = 0; r < 4; ++r) {
        const int row = m0 + wm + i * 16 + quad * 4 + r;
        Out[(size_t)row * Dn + col] = acc[i][j][r];
      }
    }
}

// ---------------------------------------------------------------------------
extern "C" void kernel_launch(void* const* d_in, const int* in_sizes, int n_in,
                              void* d_out, int out_size, void* d_ws, size_t ws_size,
                              hipStream_t stream) {
  const float* x    = (const float*)d_in[0];
  const float* vc   = (const float*)d_in[1];
  const float* e_sp = (const float*)d_in[2];
  const float* W1e  = (const float*)d_in[3];
  const float* b1e  = (const float*)d_in[4];
  const float* W2e  = (const float*)d_in[5];
  const float* b2e  = (const float*)d_in[6];
  const float* W1r  = (const float*)d_in[7];
  const float* b1r  = (const float*)d_in[8];
  const float* W2r  = (const float*)d_in[9];
  const float* b2r  = (const float*)d_in[10];
  float* out = (float*)d_out;

  // Workspace (88 MiB high-water):
  //   4096    W1eT | +1M W2eT | +2M W1rT | +3M W2rT  (bf16 transposed)
  //   +4M     compsT [D][C] bf16
  //   8M      Zdyn [B][C] bf16 (16 MiB) -> aliased as conc after K2
  //   24M     h  [B][H] bf16 (32 MiB)
  //   56M     hr [B][H] bf16 (32 MiB)
  // x_bf (16 MiB) lives in d_out (32 MiB, dead until K3 overwrites it).
  char* ws = (char*)d_ws;
  ushort* W1eT   = (ushort*)(ws + (1u << 12));
  ushort* W2eT   = (ushort*)(ws + (1u << 12) + (1u << 20));
  ushort* W1rT   = (ushort*)(ws + (1u << 12) + (2u << 20));
  ushort* W2rT   = (ushort*)(ws + (1u << 12) + (3u << 20));
  ushort* compsT = (ushort*)(ws + (1u << 12) + (4u << 20));
  ushort* Zdyn   = (ushort*)(ws + (8u << 20));   // then conc
  ushort* h_bf   = (ushort*)(ws + (24u << 20));
  ushort* hr_bf  = (ushort*)(ws + (56u << 20));
  ushort* x_bf   = (ushort*)d_out;               // scratch until K3

  // 1. prep: cvt_x + 4 coalesced transposes + smask (one hetero dispatch)
  k_prep<<<11264, 256, 0, stream>>>(x, x_bf, W1e, W1eT, W2e, W2eT,
                                    W1r, W1rT, W2r, W2rT, vc, e_sp, compsT);
  // 2. Z (standalone, clean I-cache, 2-elem interleave, literal keys)
  k_z<<<16384, 256, 0, stream>>>(Zdyn);
  // 3. G1 + G3
  k_g13<<<2048, 256, 0, stream>>>(x_bf, W1eT, b1e, h_bf, W1rT, b1r, hr_bf);
  // 4. double GEMM: e -> gate -> conc (in-place over Zdyn)
  k_dgemm<<<dim3(Cn / 128, Bn / 128), 256, 0, stream>>>(
      h_bf, W2eT, b2e, hr_bf, W2rT, b2r, Zdyn);
  // 5. out = conc @ comps
  k_gemm_out<<<dim3(Dn / 128, Bn / 128), 256, 0, stream>>>(Zdyn, compsT, out);
}